// Round 2
// baseline (1434.922 us; speedup 1.0000x reference)
//
#include <hip/hip_runtime.h>
#include <hip/hip_bf16.h>
#include <math.h>

#define BB 2
#define NN 512
#define CS 384
#define CZ 128
#define HH 12
#define CATW 2112

#define W_L_CONST 0.57735026919f
#define W_C_HALF 0.11785113019f
#define INV_SQRT_D 0.25f

#define CHJ 32      // j-chunk size for online softmax
#define NCH 16      // 512 / 32
#define ZSP 132     // zs row stride (floats)
#define PCTP 36     // pct row stride (floats)

// ---------------- Kernel 1: projections + rigid apply (2 tokens/block) ----
__global__ void k_proj(const float* __restrict__ s_i,
                       const float* __restrict__ rots,
                       const float* __restrict__ trans,
                       const float* __restrict__ wq,
                       const float* __restrict__ wk,
                       const float* __restrict__ wv,
                       const float* __restrict__ wqp,
                       const float* __restrict__ wkp,
                       const float* __restrict__ wvp,
                       float* __restrict__ qw, float* __restrict__ kw,
                       float* __restrict__ vw, float* __restrict__ tqw,
                       float* __restrict__ tkw, float* __restrict__ tvw) {
  int t0 = blockIdx.x * 2;
  __shared__ float s_row[2][CS];
  __shared__ float praw[2][576];
  __shared__ float R[2][9], T[2][3];
  int tid = threadIdx.x;
  for (int idx = tid; idx < 2 * CS; idx += 256) {
    int tok = idx / CS, c = idx % CS;
    s_row[tok][c] = s_i[(size_t)(t0 + tok) * CS + c];
  }
  if (tid < 18) R[tid / 9][tid % 9] = rots[t0 * 9 + tid];
  if (tid < 6) T[tid / 3][tid % 3] = trans[t0 * 3 + tid];
  __syncthreads();

  for (int f = tid; f < 1152; f += 256) {
    const float* wp;
    int stride;
    if (f < 576) {
      int sel = f / 192, r = f % 192;
      wp = ((sel == 0) ? wq : (sel == 1) ? wk : wv) + r;
      stride = 192;
    } else {
      int g = f - 576;
      if (g < 144)      { wp = wqp + g;        stride = 144; }
      else if (g < 288) { wp = wkp + (g - 144); stride = 144; }
      else              { wp = wvp + (g - 288); stride = 288; }
    }
    float a0 = 0.f, a1 = 0.f;
    #pragma unroll 8
    for (int c = 0; c < CS; c++) {
      float w = wp[(size_t)c * stride];
      a0 += s_row[0][c] * w;
      a1 += s_row[1][c] * w;
    }
    if (f < 576) {
      int sel = f / 192, r = f % 192;
      float* dst = (sel == 0) ? qw : (sel == 1) ? kw : vw;
      dst[(size_t)(t0 + 0) * 192 + r] = a0;
      dst[(size_t)(t0 + 1) * 192 + r] = a1;
    } else {
      int g = f - 576;
      praw[0][g] = a0;
      praw[1][g] = a1;
    }
  }
  __syncthreads();
  for (int idx = tid; idx < 1152; idx += 256) {
    int tok = idx / 576, f = idx % 576;
    int base, r;
    float* dst;
    if (f < 144)      { r = f;       base = 0;   dst = tqw + (size_t)(t0 + tok) * 144; }
    else if (f < 288) { r = f - 144; base = 144; dst = tkw + (size_t)(t0 + tok) * 144; }
    else              { r = f - 288; base = 288; dst = tvw + (size_t)(t0 + tok) * 288; }
    int hp = r / 3, x = r % 3;
    float v0 = praw[tok][base + hp * 3 + 0];
    float v1 = praw[tok][base + hp * 3 + 1];
    float v2 = praw[tok][base + hp * 3 + 2];
    dst[r] = R[tok][x * 3 + 0] * v0 + R[tok][x * 3 + 1] * v1 + R[tok][x * 3 + 2] * v2 + T[tok][x];
  }
}

// ---------------- Kernel 2 (fused): bias + logits + online softmax +
//                  o / o_hp / o_hat, single pass over z --------------------
// block per (b,i), 256 threads, z streamed in 16 chunks of 32 j-rows.
// o_hat accumulator: wave w owns heads 3w..3w+2, lane owns cols 2l,2l+1
// -> 6 scalar regs/thread, no cross-wave reduce.
__global__ void k_att(
    const float* __restrict__ z,
    const float* __restrict__ qw,
    const float* __restrict__ kw,
    const float* __restrict__ tqw,
    const float* __restrict__ tkw,
    const float* __restrict__ vw,
    const float* __restrict__ tvw,
    const float* __restrict__ gamma,
    const float* __restrict__ rots,
    const float* __restrict__ trans,
    const float* __restrict__ wb,
    float* __restrict__ catm) {
  int bi = blockIdx.x;
  int b = bi >> 9;
  int tid = threadIdx.x;
  int lane = tid & 63, wid = tid >> 6;

  // ---- shared pool (phase-overlaid) ----
  __shared__ float pool[6960];
  float* zs   = pool;            // [32][ZSP]  = 4224   (z chunk)
  float* wbs  = pool + 4224;     // 1536               (wb copy, [c][12])
  float* bp   = pool + 5760;     // 384                (bias[j][h] per chunk)
  float* pcp  = pool + 6144;     // 384                (logits, [j][12])
  float* pct  = pool + 6528;     // 12*PCTP = 432      (p, [h][j])
  // epilogue overlays:
  float* praw = pool + 6144;     // 288                (sum p*tv, normalized)
  float* ohp  = pool + 6432;     // 288                (rigid-inverted points)

  __shared__ float qrow[192], tqrow[144], gam[HH], Rm[9], Tm[3];
  __shared__ float mh[HH], sh[HH], fs[HH];

  // ---- prologue loads ----
  for (int i = tid; i < CZ * HH; i += 256) wbs[i] = wb[i];
  for (int i = tid; i < 192; i += 256) qrow[i] = qw[(size_t)bi * 192 + i];
  if (tid < 144) tqrow[tid] = tqw[(size_t)bi * 144 + tid];
  if (tid < HH) { gam[tid] = gamma[tid]; mh[tid] = -1e30f; sh[tid] = 0.f; }
  if (tid < 9) Rm[tid] = rots[bi * 9 + tid];
  if (tid < 3) Tm[tid] = trans[bi * 3 + tid];

  const float* zrow = z + (size_t)bi * NN * CZ;
  int jr0 = tid >> 5;             // 0..7 (z staging row group)
  int qq = (tid & 31) * 4;        // column quad
  {  // chunk 0 -> zs
    const float* pbz = zrow + qq;
    *(float4*)&zs[(jr0     ) * ZSP + qq] = *(const float4*)(pbz + (size_t)(jr0     ) * CZ);
    *(float4*)&zs[(jr0 +  8) * ZSP + qq] = *(const float4*)(pbz + (size_t)(jr0 +  8) * CZ);
    *(float4*)&zs[(jr0 + 16) * ZSP + qq] = *(const float4*)(pbz + (size_t)(jr0 + 16) * CZ);
    *(float4*)&zs[(jr0 + 24) * ZSP + qq] = *(const float4*)(pbz + (size_t)(jr0 + 24) * CZ);
  }

  // ---- per-thread roles ----
  int jw = wid * 8;                       // wave's j-range within chunk (bias/logits)
  int hh0 = wid * 3;                      // o_hat / softmax head base
  int c2 = lane * 2;                      // o_hat column pair
  // o / o_hp slots: s0 = tid (<192: o[h][d], else tv f=s0-192), s1 = tid+256 (tv)
  int s0 = tid, s1 = tid + 256;
  int h0 = (s0 < 192) ? (s0 >> 4) : (s0 - 192) / 24;
  bool has1 = (s1 < 480);
  int h1 = has1 ? (s1 - 192) / 24 : 0;
  float oacc0 = 0.f, oacc1 = 0.f;

  float a0x = 0.f, a0y = 0.f, a1x = 0.f, a1y = 0.f, a2x = 0.f, a2y = 0.f;

  __syncthreads();

  for (int ch = 0; ch < NCH; ch++) {
    int jb = ch * CHJ;

    // ---- prefetch next z chunk into registers (latency hides under compute)
    float4 zn0 = make_float4(0, 0, 0, 0), zn1 = zn0, zn2 = zn0, zn3 = zn0;
    if (ch < NCH - 1) {
      const float* pbz = zrow + (size_t)(jb + CHJ) * CZ + qq;
      zn0 = *(const float4*)(pbz + (size_t)(jr0     ) * CZ);
      zn1 = *(const float4*)(pbz + (size_t)(jr0 +  8) * CZ);
      zn2 = *(const float4*)(pbz + (size_t)(jr0 + 16) * CZ);
      zn3 = *(const float4*)(pbz + (size_t)(jr0 + 24) * CZ);
    }

    // ---- pair bias for this wave's 8 j: z[j,:] . wb  (register-reuse layout)
    {
      int jsub = lane >> 3, cseg = lane & 7;           // 8 j x 8 c-combs
      const float* zr = zs + (jw + jsub) * ZSP + cseg; // c = cseg + 8*i
      const float* wr = wbs + cseg * 12;
      float pb[HH];
      #pragma unroll
      for (int h = 0; h < HH; h++) pb[h] = 0.f;
      #pragma unroll
      for (int i = 0; i < 16; i++) {
        float zv = zr[8 * i];
        float4 w0 = *(const float4*)&wr[96 * i];
        float4 w1 = *(const float4*)&wr[96 * i + 4];
        float4 w2 = *(const float4*)&wr[96 * i + 8];
        pb[0] = fmaf(zv, w0.x, pb[0]);   pb[1] = fmaf(zv, w0.y, pb[1]);
        pb[2] = fmaf(zv, w0.z, pb[2]);   pb[3] = fmaf(zv, w0.w, pb[3]);
        pb[4] = fmaf(zv, w1.x, pb[4]);   pb[5] = fmaf(zv, w1.y, pb[5]);
        pb[6] = fmaf(zv, w1.z, pb[6]);   pb[7] = fmaf(zv, w1.w, pb[7]);
        pb[8] = fmaf(zv, w2.x, pb[8]);   pb[9] = fmaf(zv, w2.y, pb[9]);
        pb[10] = fmaf(zv, w2.z, pb[10]); pb[11] = fmaf(zv, w2.w, pb[11]);
      }
      #pragma unroll
      for (int h = 0; h < HH; h++) {
        pb[h] += __shfl_xor(pb[h], 1, 64);
        pb[h] += __shfl_xor(pb[h], 2, 64);
        pb[h] += __shfl_xor(pb[h], 4, 64);
      }
      if (cseg == 0) {   // same-wave consumer below: no barrier needed
        float* d = bp + (jw + jsub) * 12;
        *(float4*)&d[0] = make_float4(pb[0], pb[1], pb[2], pb[3]);
        *(float4*)&d[4] = make_float4(pb[4], pb[5], pb[6], pb[7]);
        *(float4*)&d[8] = make_float4(pb[8], pb[9], pb[10], pb[11]);
      }
    }

    // ---- logits for this wave's 8 j x 12 h (96 tasks) ----
    for (int t = lane; t < 96; t += 64) {
      int jsub2 = t / 12, h = t - jsub2 * 12;
      int jl = jw + jsub2;
      size_t grow = (size_t)(b * NN + jb + jl);
      const float4* kd = (const float4*)(kw + grow * 192 + h * 16);
      float qk = 0.f;
      #pragma unroll
      for (int q = 0; q < 4; q++) {
        float4 kv = kd[q];
        qk += qrow[h * 16 + q * 4 + 0] * kv.x + qrow[h * 16 + q * 4 + 1] * kv.y +
              qrow[h * 16 + q * 4 + 2] * kv.z + qrow[h * 16 + q * 4 + 3] * kv.w;
      }
      const float4* td = (const float4*)(tkw + grow * 144 + h * 12);
      float d2 = 0.f;
      #pragma unroll
      for (int q = 0; q < 3; q++) {
        float4 tv = td[q];
        float d0 = tqrow[h * 12 + q * 4 + 0] - tv.x;
        float d1 = tqrow[h * 12 + q * 4 + 1] - tv.y;
        float dd = tqrow[h * 12 + q * 4 + 2] - tv.z;
        float d3 = tqrow[h * 12 + q * 4 + 3] - tv.w;
        d2 += d0 * d0 + d1 * d1 + dd * dd + d3 * d3;
      }
      float bias = bp[jl * 12 + h];
      pcp[jl * 12 + h] =
          W_L_CONST * (qk * INV_SQRT_D + bias - W_C_HALF * gam[h] * d2);
    }
    __syncthreads();   // [B] logits ready

    // ---- online softmax update: wave w owns heads 3w..3w+2, lane = j ----
    if (lane < 32) {
      #pragma unroll
      for (int hh = 0; hh < 3; hh++) {
        int h = hh0 + hh;
        float v = pcp[lane * 12 + h];
        float cm = v;
        cm = fmaxf(cm, __shfl_xor(cm, 16, 32));
        cm = fmaxf(cm, __shfl_xor(cm, 8, 32));
        cm = fmaxf(cm, __shfl_xor(cm, 4, 32));
        cm = fmaxf(cm, __shfl_xor(cm, 2, 32));
        cm = fmaxf(cm, __shfl_xor(cm, 1, 32));
        float mo = mh[h];
        float nm = fmaxf(mo, cm);
        float f = __expf(mo - nm);
        float p = __expf(v - nm);
        float ps = p;
        ps += __shfl_xor(ps, 16, 32);
        ps += __shfl_xor(ps, 8, 32);
        ps += __shfl_xor(ps, 4, 32);
        ps += __shfl_xor(ps, 2, 32);
        ps += __shfl_xor(ps, 1, 32);
        if (lane == 0) { mh[h] = nm; sh[h] = sh[h] * f + ps; fs[h] = f; }
        pct[h * PCTP + lane] = p;
      }
    }
    __syncthreads();   // [C] p, fs ready

    // ---- o_hat: rescale + accumulate this chunk (3 heads x 2 cols/thread) ----
    {
      float f0 = fs[hh0], f1 = fs[hh0 + 1], f2 = fs[hh0 + 2];
      a0x *= f0; a0y *= f0; a1x *= f1; a1y *= f1; a2x *= f2; a2y *= f2;
      const float* pr0 = &pct[(hh0 + 0) * PCTP];
      const float* pr1 = &pct[(hh0 + 1) * PCTP];
      const float* pr2 = &pct[(hh0 + 2) * PCTP];
      const float* zcol = zs + c2;
      #pragma unroll
      for (int j4 = 0; j4 < 8; j4++) {
        float4 p0 = *(const float4*)&pr0[j4 * 4];
        float4 p1 = *(const float4*)&pr1[j4 * 4];
        float4 p2 = *(const float4*)&pr2[j4 * 4];
        float2 z0 = *(const float2*)&zcol[(j4 * 4 + 0) * ZSP];
        float2 z1 = *(const float2*)&zcol[(j4 * 4 + 1) * ZSP];
        float2 z2 = *(const float2*)&zcol[(j4 * 4 + 2) * ZSP];
        float2 z3 = *(const float2*)&zcol[(j4 * 4 + 3) * ZSP];
        a0x = fmaf(p0.x, z0.x, a0x); a0y = fmaf(p0.x, z0.y, a0y);
        a1x = fmaf(p1.x, z0.x, a1x); a1y = fmaf(p1.x, z0.y, a1y);
        a2x = fmaf(p2.x, z0.x, a2x); a2y = fmaf(p2.x, z0.y, a2y);
        a0x = fmaf(p0.y, z1.x, a0x); a0y = fmaf(p0.y, z1.y, a0y);
        a1x = fmaf(p1.y, z1.x, a1x); a1y = fmaf(p1.y, z1.y, a1y);
        a2x = fmaf(p2.y, z1.x, a2x); a2y = fmaf(p2.y, z1.y, a2y);
        a0x = fmaf(p0.z, z2.x, a0x); a0y = fmaf(p0.z, z2.y, a0y);
        a1x = fmaf(p1.z, z2.x, a1x); a1y = fmaf(p1.z, z2.y, a1y);
        a2x = fmaf(p2.z, z2.x, a2x); a2y = fmaf(p2.z, z2.y, a2y);
        a0x = fmaf(p0.w, z3.x, a0x); a0y = fmaf(p0.w, z3.y, a0y);
        a1x = fmaf(p1.w, z3.x, a1x); a1y = fmaf(p1.w, z3.y, a1y);
        a2x = fmaf(p2.w, z3.x, a2x); a2y = fmaf(p2.w, z3.y, a2y);
      }
    }

    // ---- o / o_hp: rescale + accumulate over all 32 j of chunk ----
    {
      oacc0 *= fs[h0];
      const float* prr = &pct[h0 * PCTP];
      if (s0 < 192) {
        const float* p = vw + ((size_t)(b * NN + jb)) * 192 + s0;
        #pragma unroll
        for (int q = 0; q < 8; q++) {
          float4 pa = *(const float4*)&prr[q * 4];
          oacc0 = fmaf(pa.x, p[0], oacc0);
          oacc0 = fmaf(pa.y, p[192], oacc0);
          oacc0 = fmaf(pa.z, p[384], oacc0);
          oacc0 = fmaf(pa.w, p[576], oacc0);
          p += 768;
        }
      } else {
        const float* p = tvw + ((size_t)(b * NN + jb)) * 288 + (s0 - 192);
        #pragma unroll
        for (int q = 0; q < 8; q++) {
          float4 pa = *(const float4*)&prr[q * 4];
          oacc0 = fmaf(pa.x, p[0], oacc0);
          oacc0 = fmaf(pa.y, p[288], oacc0);
          oacc0 = fmaf(pa.z, p[576], oacc0);
          oacc0 = fmaf(pa.w, p[864], oacc0);
          p += 1152;
        }
      }
      if (has1) {
        oacc1 *= fs[h1];
        const float* prr1 = &pct[h1 * PCTP];
        const float* p = tvw + ((size_t)(b * NN + jb)) * 288 + (s1 - 192);
        #pragma unroll
        for (int q = 0; q < 8; q++) {
          float4 pa = *(const float4*)&prr1[q * 4];
          oacc1 = fmaf(pa.x, p[0], oacc1);
          oacc1 = fmaf(pa.y, p[288], oacc1);
          oacc1 = fmaf(pa.z, p[576], oacc1);
          oacc1 = fmaf(pa.w, p[864], oacc1);
          p += 1152;
        }
      }
    }
    __syncthreads();   // [D] all zs / pct reads done

    if (ch < NCH - 1) {
      *(float4*)&zs[(jr0     ) * ZSP + qq] = zn0;
      *(float4*)&zs[(jr0 +  8) * ZSP + qq] = zn1;
      *(float4*)&zs[(jr0 + 16) * ZSP + qq] = zn2;
      *(float4*)&zs[(jr0 + 24) * ZSP + qq] = zn3;
      __syncthreads();   // [E] next chunk staged
    }
  }

  // ---- epilogue: normalize + rigid invert + writes ----
  if (tid < HH) fs[tid] = 1.0f / sh[tid];   // fs now holds 1/denominator
  __syncthreads();   // [F] inv ready

  float* crow = catm + (size_t)bi * CATW;
  {
    float i0 = fs[hh0], i1 = fs[hh0 + 1], i2 = fs[hh0 + 2];
    *(float2*)&crow[(hh0 + 0) * 128 + c2] = make_float2(a0x * i0, a0y * i0);
    *(float2*)&crow[(hh0 + 1) * 128 + c2] = make_float2(a1x * i1, a1y * i1);
    *(float2*)&crow[(hh0 + 2) * 128 + c2] = make_float2(a2x * i2, a2y * i2);
  }
  {
    float ov0 = oacc0 * fs[h0];
    if (s0 < 192) crow[1536 + s0] = ov0;
    else praw[s0 - 192] = ov0;
    if (has1) praw[s1 - 192] = oacc1 * fs[h1];
  }
  __syncthreads();   // [G] praw ready

  for (int f = tid; f < 288; f += 256) {
    int g = f / 3, x = f - g * 3;
    float v0 = praw[g * 3 + 0] - Tm[0];
    float v1 = praw[g * 3 + 1] - Tm[1];
    float v2 = praw[g * 3 + 2] - Tm[2];
    float val = Rm[0 * 3 + x] * v0 + Rm[1 * 3 + x] * v1 + Rm[2 * 3 + x] * v2;
    ohp[f] = val;
    crow[1728 + f] = val;
  }
  __syncthreads();   // [H]
  if (tid < 96) {
    float x0 = ohp[tid * 3 + 0];
    float x1 = ohp[tid * 3 + 1];
    float x2 = ohp[tid * 3 + 2];
    crow[2016 + tid] = sqrtf(x0 * x0 + x1 * x1 + x2 * x2);
  }
}

// ---------------- Kernel 4: output GEMM, split-K=4, 64x64, 4x4 reg tile ---
#define KCH 528
__global__ void k_gemm(const float* __restrict__ catm,
                       const float* __restrict__ wout,
                       float* __restrict__ pout) {
  __shared__ float As[16][68];   // [kk][m], padded
  __shared__ float Bs[16][64];   // [kk][n]
  int tid = threadIdx.x;
  int n0 = blockIdx.x * 64, m0 = blockIdx.y * 64, kbase = blockIdx.z * KCH;
  int tx = tid & 15, ty = tid >> 4;
  int sm = tid & 63, skk4 = tid >> 6;
  int bkk = tid >> 4, bn4 = (tid & 15) * 4;
  float acc[4][4] = {};
  for (int kt = 0; kt < KCH / 16; kt++) {
    int k0 = kbase + kt * 16;
    float4 ga = *(const float4*)(catm + (size_t)(m0 + sm) * CATW + k0 + skk4 * 4);
    float4 gb = *(const float4*)(wout + (size_t)(k0 + bkk) * 384 + n0 + bn4);
    __syncthreads();
    As[skk4 * 4 + 0][sm] = ga.x;
    As[skk4 * 4 + 1][sm] = ga.y;
    As[skk4 * 4 + 2][sm] = ga.z;
    As[skk4 * 4 + 3][sm] = ga.w;
    *(float4*)&Bs[bkk][bn4] = gb;
    __syncthreads();
    #pragma unroll
    for (int kk = 0; kk < 16; kk++) {
      float4 av = *(const float4*)&As[kk][ty * 4];
      float4 bv = *(const float4*)&Bs[kk][tx * 4];
      acc[0][0] += av.x * bv.x; acc[0][1] += av.x * bv.y; acc[0][2] += av.x * bv.z; acc[0][3] += av.x * bv.w;
      acc[1][0] += av.y * bv.x; acc[1][1] += av.y * bv.y; acc[1][2] += av.y * bv.z; acc[1][3] += av.y * bv.w;
      acc[2][0] += av.z * bv.x; acc[2][1] += av.z * bv.y; acc[2][2] += av.z * bv.z; acc[2][3] += av.z * bv.w;
      acc[3][0] += av.w * bv.x; acc[3][1] += av.w * bv.y; acc[3][2] += av.w * bv.z; acc[3][3] += av.w * bv.w;
    }
  }
  float* pdst = pout + (size_t)blockIdx.z * (1024 * 384);
  #pragma unroll
  for (int mm = 0; mm < 4; mm++) {
    *(float4*)&pdst[(size_t)(m0 + ty * 4 + mm) * 384 + n0 + tx * 4] =
        make_float4(acc[mm][0], acc[mm][1], acc[mm][2], acc[mm][3]);
  }
}

// ---------------- Kernel 5: split-K reduce + bias ----
__global__ void k_red(const float* __restrict__ pout,
                      const float* __restrict__ bout,
                      float* __restrict__ out) {
  int idx = blockIdx.x * 256 + threadIdx.x;
  const int TOTAL = 1024 * 384;
  float s = pout[idx] + pout[TOTAL + idx] + pout[2 * TOTAL + idx] + pout[3 * TOTAL + idx];
  out[idx] = s + bout[idx % 384];
}

extern "C" void kernel_launch(void* const* d_in, const int* in_sizes, int n_in,
                              void* d_out, int out_size, void* d_ws, size_t ws_size,
                              hipStream_t stream) {
  const float* s_i   = (const float*)d_in[0];
  const float* z     = (const float*)d_in[1];
  const float* rots  = (const float*)d_in[2];
  const float* trans = (const float*)d_in[3];
  const float* wq    = (const float*)d_in[4];
  const float* wk    = (const float*)d_in[5];
  const float* wv    = (const float*)d_in[6];
  const float* wqp   = (const float*)d_in[7];
  const float* wkp   = (const float*)d_in[8];
  const float* wvp   = (const float*)d_in[9];
  const float* wb    = (const float*)d_in[10];
  const float* gamma = (const float*)d_in[11];
  const float* wout  = (const float*)d_in[12];
  const float* bout  = (const float*)d_in[13];
  float* out = (float*)d_out;

  float* ws = (float*)d_ws;
  const size_t TOK = (size_t)BB * NN;  // 1024
  float* qw  = ws;                      // TOK*192
  float* kw  = qw + TOK * 192;
  float* vw  = kw + TOK * 192;
  float* tqw = vw + TOK * 192;          // TOK*144
  float* tkw = tqw + TOK * 144;
  float* tvw = tkw + TOK * 144;         // TOK*288
  float* bw  = tvw + TOK * 288;         // (unused slot, layout kept)
  float* catm = bw + TOK * HH * NN;     // TOK*2112
  float* pout = catm + TOK * CATW;      // 4*1024*384

  k_proj<<<BB * NN / 2, 256, 0, stream>>>(s_i, rots, trans, wq, wk, wv, wqp, wkp, wvp,
                                          qw, kw, vw, tqw, tkw, tvw);
  k_att<<<BB * NN, 256, 0, stream>>>(z, qw, kw, tqw, tkw, vw, tvw, gamma, rots, trans,
                                     wb, catm);
  dim3 gg(6, 16, 4);
  k_gemm<<<gg, 256, 0, stream>>>(catm, wout, pout);
  k_red<<<(1024 * 384) / 256, 256, 0, stream>>>(pout, bout, out);
}

// Round 3
// 1108.539 us; speedup vs baseline: 1.2944x; 1.2944x over previous
//
#include <hip/hip_runtime.h>
#include <hip/hip_bf16.h>
#include <math.h>

#define BB 2
#define NN 512
#define CS 384
#define CZ 128
#define HH 12
#define CATW 2112

#define W_L_CONST 0.57735026919f
#define W_C_HALF 0.11785113019f
#define INV_SQRT_D 0.25f

#define CHJ 32      // j-chunk size for online softmax
#define NCH 16      // 512 / 32
#define ZSP 132     // zs row stride (floats)
#define PCTP 36     // pct row stride (floats)

// ---------------- Kernel 1: projections + rigid apply (2 tokens/block) ----
__global__ void k_proj(const float* __restrict__ s_i,
                       const float* __restrict__ rots,
                       const float* __restrict__ trans,
                       const float* __restrict__ wq,
                       const float* __restrict__ wk,
                       const float* __restrict__ wv,
                       const float* __restrict__ wqp,
                       const float* __restrict__ wkp,
                       const float* __restrict__ wvp,
                       float* __restrict__ qw, float* __restrict__ kw,
                       float* __restrict__ vw, float* __restrict__ tqw,
                       float* __restrict__ tkw, float* __restrict__ tvw) {
  int t0 = blockIdx.x * 2;
  __shared__ float s_row[2][CS];
  __shared__ float praw[2][576];
  __shared__ float R[2][9], T[2][3];
  int tid = threadIdx.x;
  for (int idx = tid; idx < 2 * CS; idx += 256) {
    int tok = idx / CS, c = idx % CS;
    s_row[tok][c] = s_i[(size_t)(t0 + tok) * CS + c];
  }
  if (tid < 18) R[tid / 9][tid % 9] = rots[t0 * 9 + tid];
  if (tid < 6) T[tid / 3][tid % 3] = trans[t0 * 3 + tid];
  __syncthreads();

  for (int f = tid; f < 1152; f += 256) {
    const float* wp;
    int stride;
    if (f < 576) {
      int sel = f / 192, r = f % 192;
      wp = ((sel == 0) ? wq : (sel == 1) ? wk : wv) + r;
      stride = 192;
    } else {
      int g = f - 576;
      if (g < 144)      { wp = wqp + g;        stride = 144; }
      else if (g < 288) { wp = wkp + (g - 144); stride = 144; }
      else              { wp = wvp + (g - 288); stride = 288; }
    }
    float a0 = 0.f, a1 = 0.f;
    #pragma unroll 8
    for (int c = 0; c < CS; c++) {
      float w = wp[(size_t)c * stride];
      a0 += s_row[0][c] * w;
      a1 += s_row[1][c] * w;
    }
    if (f < 576) {
      int sel = f / 192, r = f % 192;
      float* dst = (sel == 0) ? qw : (sel == 1) ? kw : vw;
      dst[(size_t)(t0 + 0) * 192 + r] = a0;
      dst[(size_t)(t0 + 1) * 192 + r] = a1;
    } else {
      int g = f - 576;
      praw[0][g] = a0;
      praw[1][g] = a1;
    }
  }
  __syncthreads();
  for (int idx = tid; idx < 1152; idx += 256) {
    int tok = idx / 576, f = idx % 576;
    int base, r;
    float* dst;
    if (f < 144)      { r = f;       base = 0;   dst = tqw + (size_t)(t0 + tok) * 144; }
    else if (f < 288) { r = f - 144; base = 144; dst = tkw + (size_t)(t0 + tok) * 144; }
    else              { r = f - 288; base = 288; dst = tvw + (size_t)(t0 + tok) * 288; }
    int hp = r / 3, x = r % 3;
    float v0 = praw[tok][base + hp * 3 + 0];
    float v1 = praw[tok][base + hp * 3 + 1];
    float v2 = praw[tok][base + hp * 3 + 2];
    dst[r] = R[tok][x * 3 + 0] * v0 + R[tok][x * 3 + 1] * v1 + R[tok][x * 3 + 2] * v2 + T[tok][x];
  }
}

// ---------------- Kernel 2 (fused): bias + logits + online softmax +
//                  o / o_hp / o_hat, single pass over z --------------------
// block per (b,i), 256 threads, z streamed in 16 chunks of 32 j-rows.
// amdgpu_waves_per_eu(2,4): overrides the memory-bound perf-hint that
// capped the allocator at 64 VGPRs (8 waves/EU target) and caused ~2.7 GB
// of scratch spill traffic in rounds 1-2. Peak live set is ~110 VGPRs.
__global__ __launch_bounds__(256)
__attribute__((amdgpu_waves_per_eu(2, 4)))
void k_att(
    const float* __restrict__ z,
    const float* __restrict__ qw,
    const float* __restrict__ kw,
    const float* __restrict__ tqw,
    const float* __restrict__ tkw,
    const float* __restrict__ vw,
    const float* __restrict__ tvw,
    const float* __restrict__ gamma,
    const float* __restrict__ rots,
    const float* __restrict__ trans,
    const float* __restrict__ wb,
    float* __restrict__ catm) {
  int bi = blockIdx.x;
  int b = bi >> 9;
  int tid = threadIdx.x;
  int lane = tid & 63, wid = tid >> 6;

  // ---- shared pool (phase-overlaid) ----
  __shared__ float pool[6960];
  float* zs   = pool;            // [32][ZSP]  = 4224   (z chunk)
  float* wbs  = pool + 4224;     // 1536               (wb copy, [c][12])
  float* bp   = pool + 5760;     // 384                (bias[j][h] per chunk)
  float* pcp  = pool + 6144;     // 384                (logits, [j][12])
  float* pct  = pool + 6528;     // 12*PCTP = 432      (p, [h][j])
  // epilogue overlays:
  float* praw = pool + 6144;     // 288                (sum p*tv, normalized)
  float* ohp  = pool + 6432;     // 288                (rigid-inverted points)

  __shared__ float qrow[192], tqrow[144], gam[HH], Rm[9], Tm[3];
  __shared__ float mh[HH], sh[HH], fs[HH];

  // ---- prologue loads ----
  for (int i = tid; i < CZ * HH; i += 256) wbs[i] = wb[i];
  for (int i = tid; i < 192; i += 256) qrow[i] = qw[(size_t)bi * 192 + i];
  if (tid < 144) tqrow[tid] = tqw[(size_t)bi * 144 + tid];
  if (tid < HH) { gam[tid] = gamma[tid]; mh[tid] = -1e30f; sh[tid] = 0.f; }
  if (tid < 9) Rm[tid] = rots[bi * 9 + tid];
  if (tid < 3) Tm[tid] = trans[bi * 3 + tid];

  const float* zrow = z + (size_t)bi * NN * CZ;
  int jr0 = tid >> 5;             // 0..7 (z staging row group)
  int qq = (tid & 31) * 4;        // column quad
  {  // chunk 0 -> zs
    const float* pbz = zrow + qq;
    *(float4*)&zs[(jr0     ) * ZSP + qq] = *(const float4*)(pbz + (size_t)(jr0     ) * CZ);
    *(float4*)&zs[(jr0 +  8) * ZSP + qq] = *(const float4*)(pbz + (size_t)(jr0 +  8) * CZ);
    *(float4*)&zs[(jr0 + 16) * ZSP + qq] = *(const float4*)(pbz + (size_t)(jr0 + 16) * CZ);
    *(float4*)&zs[(jr0 + 24) * ZSP + qq] = *(const float4*)(pbz + (size_t)(jr0 + 24) * CZ);
  }

  // ---- per-thread roles ----
  int jw = wid * 8;                       // wave's j-range within chunk (bias/logits)
  int hh0 = wid * 3;                      // o_hat / softmax head base
  int c2 = lane * 2;                      // o_hat column pair
  // o / o_hp slots: s0 = tid (<192: o[h][d], else tv f=s0-192), s1 = tid+256 (tv)
  int s0 = tid, s1 = tid + 256;
  int h0 = (s0 < 192) ? (s0 >> 4) : (s0 - 192) / 24;
  bool has1 = (s1 < 480);
  int h1 = has1 ? (s1 - 192) / 24 : 0;
  float oacc0 = 0.f, oacc1 = 0.f;

  float a0x = 0.f, a0y = 0.f, a1x = 0.f, a1y = 0.f, a2x = 0.f, a2y = 0.f;

  __syncthreads();

  for (int ch = 0; ch < NCH; ch++) {
    int jb = ch * CHJ;

    // ---- prefetch next z chunk into registers (latency hides under compute)
    float4 zn0 = make_float4(0, 0, 0, 0), zn1 = zn0, zn2 = zn0, zn3 = zn0;
    if (ch < NCH - 1) {
      const float* pbz = zrow + (size_t)(jb + CHJ) * CZ + qq;
      zn0 = *(const float4*)(pbz + (size_t)(jr0     ) * CZ);
      zn1 = *(const float4*)(pbz + (size_t)(jr0 +  8) * CZ);
      zn2 = *(const float4*)(pbz + (size_t)(jr0 + 16) * CZ);
      zn3 = *(const float4*)(pbz + (size_t)(jr0 + 24) * CZ);
    }

    // ---- pair bias for this wave's 8 j: z[j,:] . wb  (register-reuse layout)
    {
      int jsub = lane >> 3, cseg = lane & 7;           // 8 j x 8 c-combs
      const float* zr = zs + (jw + jsub) * ZSP + cseg; // c = cseg + 8*i
      const float* wr = wbs + cseg * 12;
      float pb[HH];
      #pragma unroll
      for (int h = 0; h < HH; h++) pb[h] = 0.f;
      #pragma unroll
      for (int i = 0; i < 16; i++) {
        float zv = zr[8 * i];
        float4 w0 = *(const float4*)&wr[96 * i];
        float4 w1 = *(const float4*)&wr[96 * i + 4];
        float4 w2 = *(const float4*)&wr[96 * i + 8];
        pb[0] = fmaf(zv, w0.x, pb[0]);   pb[1] = fmaf(zv, w0.y, pb[1]);
        pb[2] = fmaf(zv, w0.z, pb[2]);   pb[3] = fmaf(zv, w0.w, pb[3]);
        pb[4] = fmaf(zv, w1.x, pb[4]);   pb[5] = fmaf(zv, w1.y, pb[5]);
        pb[6] = fmaf(zv, w1.z, pb[6]);   pb[7] = fmaf(zv, w1.w, pb[7]);
        pb[8] = fmaf(zv, w2.x, pb[8]);   pb[9] = fmaf(zv, w2.y, pb[9]);
        pb[10] = fmaf(zv, w2.z, pb[10]); pb[11] = fmaf(zv, w2.w, pb[11]);
      }
      #pragma unroll
      for (int h = 0; h < HH; h++) {
        pb[h] += __shfl_xor(pb[h], 1, 64);
        pb[h] += __shfl_xor(pb[h], 2, 64);
        pb[h] += __shfl_xor(pb[h], 4, 64);
      }
      if (cseg == 0) {   // same-wave consumer below: no barrier needed
        float* d = bp + (jw + jsub) * 12;
        *(float4*)&d[0] = make_float4(pb[0], pb[1], pb[2], pb[3]);
        *(float4*)&d[4] = make_float4(pb[4], pb[5], pb[6], pb[7]);
        *(float4*)&d[8] = make_float4(pb[8], pb[9], pb[10], pb[11]);
      }
    }

    // ---- logits for this wave's 8 j x 12 h (96 tasks) ----
    for (int t = lane; t < 96; t += 64) {
      int jsub2 = t / 12, h = t - jsub2 * 12;
      int jl = jw + jsub2;
      size_t grow = (size_t)(b * NN + jb + jl);
      const float4* kd = (const float4*)(kw + grow * 192 + h * 16);
      float qk = 0.f;
      #pragma unroll
      for (int q = 0; q < 4; q++) {
        float4 kv = kd[q];
        qk += qrow[h * 16 + q * 4 + 0] * kv.x + qrow[h * 16 + q * 4 + 1] * kv.y +
              qrow[h * 16 + q * 4 + 2] * kv.z + qrow[h * 16 + q * 4 + 3] * kv.w;
      }
      const float4* td = (const float4*)(tkw + grow * 144 + h * 12);
      float d2 = 0.f;
      #pragma unroll
      for (int q = 0; q < 3; q++) {
        float4 tv = td[q];
        float d0 = tqrow[h * 12 + q * 4 + 0] - tv.x;
        float d1 = tqrow[h * 12 + q * 4 + 1] - tv.y;
        float dd = tqrow[h * 12 + q * 4 + 2] - tv.z;
        float d3 = tqrow[h * 12 + q * 4 + 3] - tv.w;
        d2 += d0 * d0 + d1 * d1 + dd * dd + d3 * d3;
      }
      float bias = bp[jl * 12 + h];
      pcp[jl * 12 + h] =
          W_L_CONST * (qk * INV_SQRT_D + bias - W_C_HALF * gam[h] * d2);
    }
    __syncthreads();   // [B] logits ready

    // ---- online softmax update: wave w owns heads 3w..3w+2, lane = j ----
    if (lane < 32) {
      #pragma unroll
      for (int hh = 0; hh < 3; hh++) {
        int h = hh0 + hh;
        float v = pcp[lane * 12 + h];
        float cm = v;
        cm = fmaxf(cm, __shfl_xor(cm, 16, 32));
        cm = fmaxf(cm, __shfl_xor(cm, 8, 32));
        cm = fmaxf(cm, __shfl_xor(cm, 4, 32));
        cm = fmaxf(cm, __shfl_xor(cm, 2, 32));
        cm = fmaxf(cm, __shfl_xor(cm, 1, 32));
        float mo = mh[h];
        float nm = fmaxf(mo, cm);
        float f = __expf(mo - nm);
        float p = __expf(v - nm);
        float ps = p;
        ps += __shfl_xor(ps, 16, 32);
        ps += __shfl_xor(ps, 8, 32);
        ps += __shfl_xor(ps, 4, 32);
        ps += __shfl_xor(ps, 2, 32);
        ps += __shfl_xor(ps, 1, 32);
        if (lane == 0) { mh[h] = nm; sh[h] = sh[h] * f + ps; fs[h] = f; }
        pct[h * PCTP + lane] = p;
      }
    }
    __syncthreads();   // [C] p, fs ready

    // ---- o_hat: rescale + accumulate this chunk (3 heads x 2 cols/thread) ----
    {
      float f0 = fs[hh0], f1 = fs[hh0 + 1], f2 = fs[hh0 + 2];
      a0x *= f0; a0y *= f0; a1x *= f1; a1y *= f1; a2x *= f2; a2y *= f2;
      const float* pr0 = &pct[(hh0 + 0) * PCTP];
      const float* pr1 = &pct[(hh0 + 1) * PCTP];
      const float* pr2 = &pct[(hh0 + 2) * PCTP];
      const float* zcol = zs + c2;
      #pragma unroll
      for (int j4 = 0; j4 < 8; j4++) {
        float4 p0 = *(const float4*)&pr0[j4 * 4];
        float4 p1 = *(const float4*)&pr1[j4 * 4];
        float4 p2 = *(const float4*)&pr2[j4 * 4];
        float2 z0 = *(const float2*)&zcol[(j4 * 4 + 0) * ZSP];
        float2 z1 = *(const float2*)&zcol[(j4 * 4 + 1) * ZSP];
        float2 z2 = *(const float2*)&zcol[(j4 * 4 + 2) * ZSP];
        float2 z3 = *(const float2*)&zcol[(j4 * 4 + 3) * ZSP];
        a0x = fmaf(p0.x, z0.x, a0x); a0y = fmaf(p0.x, z0.y, a0y);
        a1x = fmaf(p1.x, z0.x, a1x); a1y = fmaf(p1.x, z0.y, a1y);
        a2x = fmaf(p2.x, z0.x, a2x); a2y = fmaf(p2.x, z0.y, a2y);
        a0x = fmaf(p0.y, z1.x, a0x); a0y = fmaf(p0.y, z1.y, a0y);
        a1x = fmaf(p1.y, z1.x, a1x); a1y = fmaf(p1.y, z1.y, a1y);
        a2x = fmaf(p2.y, z1.x, a2x); a2y = fmaf(p2.y, z1.y, a2y);
        a0x = fmaf(p0.z, z2.x, a0x); a0y = fmaf(p0.z, z2.y, a0y);
        a1x = fmaf(p1.z, z2.x, a1x); a1y = fmaf(p1.z, z2.y, a1y);
        a2x = fmaf(p2.z, z2.x, a2x); a2y = fmaf(p2.z, z2.y, a2y);
        a0x = fmaf(p0.w, z3.x, a0x); a0y = fmaf(p0.w, z3.y, a0y);
        a1x = fmaf(p1.w, z3.x, a1x); a1y = fmaf(p1.w, z3.y, a1y);
        a2x = fmaf(p2.w, z3.x, a2x); a2y = fmaf(p2.w, z3.y, a2y);
      }
    }

    // ---- o / o_hp: rescale + accumulate over all 32 j of chunk ----
    {
      oacc0 *= fs[h0];
      const float* prr = &pct[h0 * PCTP];
      if (s0 < 192) {
        const float* p = vw + ((size_t)(b * NN + jb)) * 192 + s0;
        #pragma unroll
        for (int q = 0; q < 8; q++) {
          float4 pa = *(const float4*)&prr[q * 4];
          oacc0 = fmaf(pa.x, p[0], oacc0);
          oacc0 = fmaf(pa.y, p[192], oacc0);
          oacc0 = fmaf(pa.z, p[384], oacc0);
          oacc0 = fmaf(pa.w, p[576], oacc0);
          p += 768;
        }
      } else {
        const float* p = tvw + ((size_t)(b * NN + jb)) * 288 + (s0 - 192);
        #pragma unroll
        for (int q = 0; q < 8; q++) {
          float4 pa = *(const float4*)&prr[q * 4];
          oacc0 = fmaf(pa.x, p[0], oacc0);
          oacc0 = fmaf(pa.y, p[288], oacc0);
          oacc0 = fmaf(pa.z, p[576], oacc0);
          oacc0 = fmaf(pa.w, p[864], oacc0);
          p += 1152;
        }
      }
      if (has1) {
        oacc1 *= fs[h1];
        const float* prr1 = &pct[h1 * PCTP];
        const float* p = tvw + ((size_t)(b * NN + jb)) * 288 + (s1 - 192);
        #pragma unroll
        for (int q = 0; q < 8; q++) {
          float4 pa = *(const float4*)&prr1[q * 4];
          oacc1 = fmaf(pa.x, p[0], oacc1);
          oacc1 = fmaf(pa.y, p[288], oacc1);
          oacc1 = fmaf(pa.z, p[576], oacc1);
          oacc1 = fmaf(pa.w, p[864], oacc1);
          p += 1152;
        }
      }
    }
    __syncthreads();   // [D] all zs / pct reads done

    if (ch < NCH - 1) {
      *(float4*)&zs[(jr0     ) * ZSP + qq] = zn0;
      *(float4*)&zs[(jr0 +  8) * ZSP + qq] = zn1;
      *(float4*)&zs[(jr0 + 16) * ZSP + qq] = zn2;
      *(float4*)&zs[(jr0 + 24) * ZSP + qq] = zn3;
      __syncthreads();   // [E] next chunk staged
    }
  }

  // ---- epilogue: normalize + rigid invert + writes ----
  if (tid < HH) fs[tid] = 1.0f / sh[tid];   // fs now holds 1/denominator
  __syncthreads();   // [F] inv ready

  float* crow = catm + (size_t)bi * CATW;
  {
    float i0 = fs[hh0], i1 = fs[hh0 + 1], i2 = fs[hh0 + 2];
    *(float2*)&crow[(hh0 + 0) * 128 + c2] = make_float2(a0x * i0, a0y * i0);
    *(float2*)&crow[(hh0 + 1) * 128 + c2] = make_float2(a1x * i1, a1y * i1);
    *(float2*)&crow[(hh0 + 2) * 128 + c2] = make_float2(a2x * i2, a2y * i2);
  }
  {
    float ov0 = oacc0 * fs[h0];
    if (s0 < 192) crow[1536 + s0] = ov0;
    else praw[s0 - 192] = ov0;
    if (has1) praw[s1 - 192] = oacc1 * fs[h1];
  }
  __syncthreads();   // [G] praw ready

  for (int f = tid; f < 288; f += 256) {
    int g = f / 3, x = f - g * 3;
    float v0 = praw[g * 3 + 0] - Tm[0];
    float v1 = praw[g * 3 + 1] - Tm[1];
    float v2 = praw[g * 3 + 2] - Tm[2];
    float val = Rm[0 * 3 + x] * v0 + Rm[1 * 3 + x] * v1 + Rm[2 * 3 + x] * v2;
    ohp[f] = val;
    crow[1728 + f] = val;
  }
  __syncthreads();   // [H]
  if (tid < 96) {
    float x0 = ohp[tid * 3 + 0];
    float x1 = ohp[tid * 3 + 1];
    float x2 = ohp[tid * 3 + 2];
    crow[2016 + tid] = sqrtf(x0 * x0 + x1 * x1 + x2 * x2);
  }
}

// ---------------- Kernel 4: output GEMM, split-K=4, 64x64, 4x4 reg tile ---
#define KCH 528
__global__ void k_gemm(const float* __restrict__ catm,
                       const float* __restrict__ wout,
                       float* __restrict__ pout) {
  __shared__ float As[16][68];   // [kk][m], padded
  __shared__ float Bs[16][64];   // [kk][n]
  int tid = threadIdx.x;
  int n0 = blockIdx.x * 64, m0 = blockIdx.y * 64, kbase = blockIdx.z * KCH;
  int tx = tid & 15, ty = tid >> 4;
  int sm = tid & 63, skk4 = tid >> 6;
  int bkk = tid >> 4, bn4 = (tid & 15) * 4;
  float acc[4][4] = {};
  for (int kt = 0; kt < KCH / 16; kt++) {
    int k0 = kbase + kt * 16;
    float4 ga = *(const float4*)(catm + (size_t)(m0 + sm) * CATW + k0 + skk4 * 4);
    float4 gb = *(const float4*)(wout + (size_t)(k0 + bkk) * 384 + n0 + bn4);
    __syncthreads();
    As[skk4 * 4 + 0][sm] = ga.x;
    As[skk4 * 4 + 1][sm] = ga.y;
    As[skk4 * 4 + 2][sm] = ga.z;
    As[skk4 * 4 + 3][sm] = ga.w;
    *(float4*)&Bs[bkk][bn4] = gb;
    __syncthreads();
    #pragma unroll
    for (int kk = 0; kk < 16; kk++) {
      float4 av = *(const float4*)&As[kk][ty * 4];
      float4 bv = *(const float4*)&Bs[kk][tx * 4];
      acc[0][0] += av.x * bv.x; acc[0][1] += av.x * bv.y; acc[0][2] += av.x * bv.z; acc[0][3] += av.x * bv.w;
      acc[1][0] += av.y * bv.x; acc[1][1] += av.y * bv.y; acc[1][2] += av.y * bv.z; acc[1][3] += av.y * bv.w;
      acc[2][0] += av.z * bv.x; acc[2][1] += av.z * bv.y; acc[2][2] += av.z * bv.z; acc[2][3] += av.z * bv.w;
      acc[3][0] += av.w * bv.x; acc[3][1] += av.w * bv.y; acc[3][2] += av.w * bv.z; acc[3][3] += av.w * bv.w;
    }
  }
  float* pdst = pout + (size_t)blockIdx.z * (1024 * 384);
  #pragma unroll
  for (int mm = 0; mm < 4; mm++) {
    *(float4*)&pdst[(size_t)(m0 + ty * 4 + mm) * 384 + n0 + tx * 4] =
        make_float4(acc[mm][0], acc[mm][1], acc[mm][2], acc[mm][3]);
  }
}

// ---------------- Kernel 5: split-K reduce + bias ----
__global__ void k_red(const float* __restrict__ pout,
                      const float* __restrict__ bout,
                      float* __restrict__ out) {
  int idx = blockIdx.x * 256 + threadIdx.x;
  const int TOTAL = 1024 * 384;
  float s = pout[idx] + pout[TOTAL + idx] + pout[2 * TOTAL + idx] + pout[3 * TOTAL + idx];
  out[idx] = s + bout[idx % 384];
}

extern "C" void kernel_launch(void* const* d_in, const int* in_sizes, int n_in,
                              void* d_out, int out_size, void* d_ws, size_t ws_size,
                              hipStream_t stream) {
  const float* s_i   = (const float*)d_in[0];
  const float* z     = (const float*)d_in[1];
  const float* rots  = (const float*)d_in[2];
  const float* trans = (const float*)d_in[3];
  const float* wq    = (const float*)d_in[4];
  const float* wk    = (const float*)d_in[5];
  const float* wv    = (const float*)d_in[6];
  const float* wqp   = (const float*)d_in[7];
  const float* wkp   = (const float*)d_in[8];
  const float* wvp   = (const float*)d_in[9];
  const float* wb    = (const float*)d_in[10];
  const float* gamma = (const float*)d_in[11];
  const float* wout  = (const float*)d_in[12];
  const float* bout  = (const float*)d_in[13];
  float* out = (float*)d_out;

  float* ws = (float*)d_ws;
  const size_t TOK = (size_t)BB * NN;  // 1024
  float* qw  = ws;                      // TOK*192
  float* kw  = qw + TOK * 192;
  float* vw  = kw + TOK * 192;
  float* tqw = vw + TOK * 192;          // TOK*144
  float* tkw = tqw + TOK * 144;
  float* tvw = tkw + TOK * 144;         // TOK*288
  float* bw  = tvw + TOK * 288;         // (unused slot, layout kept)
  float* catm = bw + TOK * HH * NN;     // TOK*2112
  float* pout = catm + TOK * CATW;      // 4*1024*384

  k_proj<<<BB * NN / 2, 256, 0, stream>>>(s_i, rots, trans, wq, wk, wv, wqp, wkp, wvp,
                                          qw, kw, vw, tqw, tkw, tvw);
  k_att<<<BB * NN, 256, 0, stream>>>(z, qw, kw, tqw, tkw, vw, tvw, gamma, rots, trans,
                                     wb, catm);
  dim3 gg(6, 16, 4);
  k_gemm<<<gg, 256, 0, stream>>>(catm, wout, pout);
  k_red<<<(1024 * 384) / 256, 256, 0, stream>>>(pout, bout, out);
}

// Round 5
// 757.200 us; speedup vs baseline: 1.8950x; 1.4640x over previous
//
#include <hip/hip_runtime.h>
#include <hip/hip_bf16.h>
#include <math.h>

#define BB 2
#define NN 512
#define CS 384
#define CZ 128
#define HH 12
#define CATW 2112

#define W_L_CONST 0.57735026919f
#define W_C_HALF 0.11785113019f
#define INV_SQRT_D 0.25f
#define LGP 516   // padded row stride for lg[h][*]

// ---------------- Kernel 1: projections + rigid apply (2 tokens/block) ----
__global__ void k_proj(const float* __restrict__ s_i,
                       const float* __restrict__ rots,
                       const float* __restrict__ trans,
                       const float* __restrict__ wq,
                       const float* __restrict__ wk,
                       const float* __restrict__ wv,
                       const float* __restrict__ wqp,
                       const float* __restrict__ wkp,
                       const float* __restrict__ wvp,
                       float* __restrict__ qw, float* __restrict__ kw,
                       float* __restrict__ vw, float* __restrict__ tqw,
                       float* __restrict__ tkw, float* __restrict__ tvw) {
  int t0 = blockIdx.x * 2;
  __shared__ float s_row[2][CS];
  __shared__ float praw[2][576];
  __shared__ float R[2][9], T[2][3];
  int tid = threadIdx.x;
  for (int idx = tid; idx < 2 * CS; idx += 256) {
    int tok = idx / CS, c = idx % CS;
    s_row[tok][c] = s_i[(size_t)(t0 + tok) * CS + c];
  }
  if (tid < 18) R[tid / 9][tid % 9] = rots[t0 * 9 + tid];
  if (tid < 6) T[tid / 3][tid % 3] = trans[t0 * 3 + tid];
  __syncthreads();

  for (int f = tid; f < 1152; f += 256) {
    const float* wp;
    int stride;
    if (f < 576) {
      int sel = f / 192, r = f % 192;
      wp = ((sel == 0) ? wq : (sel == 1) ? wk : wv) + r;
      stride = 192;
    } else {
      int g = f - 576;
      if (g < 144)      { wp = wqp + g;        stride = 144; }
      else if (g < 288) { wp = wkp + (g - 144); stride = 144; }
      else              { wp = wvp + (g - 288); stride = 288; }
    }
    float a0 = 0.f, a1 = 0.f;
    #pragma unroll 8
    for (int c = 0; c < CS; c++) {
      float w = wp[(size_t)c * stride];
      a0 += s_row[0][c] * w;
      a1 += s_row[1][c] * w;
    }
    if (f < 576) {
      int sel = f / 192, r = f % 192;
      float* dst = (sel == 0) ? qw : (sel == 1) ? kw : vw;
      dst[(size_t)(t0 + 0) * 192 + r] = a0;
      dst[(size_t)(t0 + 1) * 192 + r] = a1;
    } else {
      int g = f - 576;
      praw[0][g] = a0;
      praw[1][g] = a1;
    }
  }
  __syncthreads();
  for (int idx = tid; idx < 1152; idx += 256) {
    int tok = idx / 576, f = idx % 576;
    int base, r;
    float* dst;
    if (f < 144)      { r = f;       base = 0;   dst = tqw + (size_t)(t0 + tok) * 144; }
    else if (f < 288) { r = f - 144; base = 144; dst = tkw + (size_t)(t0 + tok) * 144; }
    else              { r = f - 288; base = 288; dst = tvw + (size_t)(t0 + tok) * 288; }
    int hp = r / 3, x = r % 3;
    float v0 = praw[tok][base + hp * 3 + 0];
    float v1 = praw[tok][base + hp * 3 + 1];
    float v2 = praw[tok][base + hp * 3 + 2];
    dst[r] = R[tok][x * 3 + 0] * v0 + R[tok][x * 3 + 1] * v1 + R[tok][x * 3 + 2] * v2 + T[tok][x];
  }
}

// ---------------- Kernel 2: pair bias GEMM (z @ wb) -----------------------
// 128 rows/block, 2 rows/lane, wave w owns heads 3w..3w+2.
// wbt transposed -> weight reads are wave-broadcast b128;
// zt chunk-XOR-swizzled (write AND read sides) -> b128 reads bank-spread.
#define BR 128
__global__ void k_bias(const float* __restrict__ z,
                       const float* __restrict__ wb,
                       float* __restrict__ bw) {
  __shared__ float zt[BR * 128];      // [row][ (c4 ^ (row&7)) quad ]
  __shared__ float wbt[12][128];      // wb transposed [h][c]
  __shared__ float bbs[BR][13];
  int tid = threadIdx.x;
  int r0 = blockIdx.x * BR;
  int bi = r0 >> 9, j0 = r0 & 511;

  for (int idx = tid; idx < CZ * HH; idx += 256) {
    int h = idx >> 7, c = idx & 127;
    wbt[h][c] = wb[c * HH + h];
  }
  const float* zbase = z + (size_t)r0 * CZ;
  #pragma unroll
  for (int s = 0; s < 16; s++) {
    int idx = tid + s * 256;          // 4096 float4 chunks
    int row = idx >> 5, c4 = idx & 31;
    float4 v = *(const float4*)(zbase + (size_t)row * CZ + c4 * 4);
    *(float4*)&zt[row * 128 + ((c4 ^ (row & 7)) << 2)] = v;
  }
  __syncthreads();

  int lane = tid & 63, wid = tid >> 6;
  int hb = wid * 3;
  int rA = lane, rB = lane + 64;
  int sA = rA & 7, sB = rB & 7;
  const float* w0 = wbt[hb + 0];
  const float* w1 = wbt[hb + 1];
  const float* w2 = wbt[hb + 2];
  const float* zArow = &zt[rA * 128];
  const float* zBrow = &zt[rB * 128];
  float aA0 = 0.f, aA1 = 0.f, aA2 = 0.f, aB0 = 0.f, aB1 = 0.f, aB2 = 0.f;
  #pragma unroll 8
  for (int c4 = 0; c4 < 32; c4++) {
    float4 zA = *(const float4*)&zArow[(c4 ^ sA) << 2];
    float4 zB = *(const float4*)&zBrow[(c4 ^ sB) << 2];
    float4 v0 = *(const float4*)&w0[c4 << 2];
    float4 v1 = *(const float4*)&w1[c4 << 2];
    float4 v2 = *(const float4*)&w2[c4 << 2];
    aA0 = fmaf(zA.x, v0.x, aA0); aA0 = fmaf(zA.y, v0.y, aA0);
    aA0 = fmaf(zA.z, v0.z, aA0); aA0 = fmaf(zA.w, v0.w, aA0);
    aA1 = fmaf(zA.x, v1.x, aA1); aA1 = fmaf(zA.y, v1.y, aA1);
    aA1 = fmaf(zA.z, v1.z, aA1); aA1 = fmaf(zA.w, v1.w, aA1);
    aA2 = fmaf(zA.x, v2.x, aA2); aA2 = fmaf(zA.y, v2.y, aA2);
    aA2 = fmaf(zA.z, v2.z, aA2); aA2 = fmaf(zA.w, v2.w, aA2);
    aB0 = fmaf(zB.x, v0.x, aB0); aB0 = fmaf(zB.y, v0.y, aB0);
    aB0 = fmaf(zB.z, v0.z, aB0); aB0 = fmaf(zB.w, v0.w, aB0);
    aB1 = fmaf(zB.x, v1.x, aB1); aB1 = fmaf(zB.y, v1.y, aB1);
    aB1 = fmaf(zB.z, v1.z, aB1); aB1 = fmaf(zB.w, v1.w, aB1);
    aB2 = fmaf(zB.x, v2.x, aB2); aB2 = fmaf(zB.y, v2.y, aB2);
    aB2 = fmaf(zB.z, v2.z, aB2); aB2 = fmaf(zB.w, v2.w, aB2);
  }
  bbs[rA][hb + 0] = aA0; bbs[rA][hb + 1] = aA1; bbs[rA][hb + 2] = aA2;
  bbs[rB][hb + 0] = aB0; bbs[rB][hb + 1] = aB1; bbs[rB][hb + 2] = aB2;
  __syncthreads();

  #pragma unroll
  for (int s = 0; s < 6; s++) {
    int idx = tid + s * 256;          // 1536 outputs
    int h = idx >> 7, jl = idx & 127;
    bw[((size_t)bi * HH + h) * NN + j0 + jl] = bbs[jl][h];
  }
}

// ---------------- Kernel 3: fused logits+softmax+o/o_hp+o_hat ------------
// block per (b,i), 256 threads  (round-0 proven version, 164 us)
__global__ void k_att(const float* __restrict__ z,
                      const float* __restrict__ qw,
                      const float* __restrict__ kw,
                      const float* __restrict__ tqw,
                      const float* __restrict__ tkw,
                      const float* __restrict__ vw,
                      const float* __restrict__ tvw,
                      const float* __restrict__ gamma,
                      const float* __restrict__ rots,
                      const float* __restrict__ trans,
                      const float* __restrict__ bw,
                      float* __restrict__ catm) {
  int bi = blockIdx.x;
  int b = bi / NN;
  __shared__ float lg[HH][LGP];         // logits -> a -> (reused) o_hat partials
  __shared__ float opart[4][480];
  __shared__ float qrow[192], tqrow[144], gam[HH];
  __shared__ float rm[HH][4], rs[HH][4];
  __shared__ float praw[288], ohp[288], R[9], T[3];
  int tid = threadIdx.x;
  int lane = tid & 63, wid = tid >> 6;

  const float* bwrow = bw + (size_t)bi * (HH * NN);
  for (int idx = tid; idx < HH * NN; idx += 256)
    lg[idx >> 9][idx & 511] = bwrow[idx];
  for (int idx = tid; idx < 192; idx += 256) qrow[idx] = qw[(size_t)bi * 192 + idx];
  if (tid < 144) tqrow[tid] = tqw[(size_t)bi * 144 + tid];
  if (tid < HH) gam[tid] = gamma[tid];
  if (tid < 9) R[tid] = rots[bi * 9 + tid];
  if (tid < 3) T[tid] = trans[bi * 3 + tid];
  __syncthreads();

  // ---- logits: 6144 tasks = 24 * 256 ----
  for (int s = 0; s < 24; s++) {
    int task = tid + s * 256;
    int j = task / 12, h = task % 12;
    const float4* kd = (const float4*)(kw + ((size_t)(b * NN + j)) * 192 + h * 16);
    float as = 0.f;
    #pragma unroll
    for (int q = 0; q < 4; q++) {
      float4 kv = kd[q];
      as += qrow[h * 16 + q * 4 + 0] * kv.x + qrow[h * 16 + q * 4 + 1] * kv.y +
            qrow[h * 16 + q * 4 + 2] * kv.z + qrow[h * 16 + q * 4 + 3] * kv.w;
    }
    const float4* td = (const float4*)(tkw + ((size_t)(b * NN + j)) * 144 + h * 12);
    float d2 = 0.f;
    #pragma unroll
    for (int q = 0; q < 3; q++) {
      float4 tv = td[q];
      float d0 = tqrow[h * 12 + q * 4 + 0] - tv.x;
      float d1 = tqrow[h * 12 + q * 4 + 1] - tv.y;
      float d2_ = tqrow[h * 12 + q * 4 + 2] - tv.z;
      float d3 = tqrow[h * 12 + q * 4 + 3] - tv.w;
      d2 += d0 * d0 + d1 * d1 + d2_ * d2_ + d3 * d3;
    }
    lg[h][j] = W_L_CONST * (as * INV_SQRT_D + lg[h][j] - W_C_HALF * gam[h] * d2);
  }
  __syncthreads();

  // ---- softmax ----
  #pragma unroll
  for (int h = 0; h < HH; h++) {
    float m = fmaxf(lg[h][tid], lg[h][tid + 256]);
    #pragma unroll
    for (int off = 32; off >= 1; off >>= 1) m = fmaxf(m, __shfl_xor(m, off, 64));
    if (lane == 0) rm[h][wid] = m;
  }
  __syncthreads();
  #pragma unroll
  for (int h = 0; h < HH; h++) {
    float mx = fmaxf(fmaxf(rm[h][0], rm[h][1]), fmaxf(rm[h][2], rm[h][3]));
    float e0 = __expf(lg[h][tid] - mx);
    float e1 = __expf(lg[h][tid + 256] - mx);
    lg[h][tid] = e0;
    lg[h][tid + 256] = e1;
    float s = e0 + e1;
    #pragma unroll
    for (int off = 32; off >= 1; off >>= 1) s += __shfl_xor(s, off, 64);
    if (lane == 0) rs[h][wid] = s;
  }
  __syncthreads();
  #pragma unroll
  for (int h = 0; h < HH; h++) {
    float inv = 1.0f / (rs[h][0] + rs[h][1] + rs[h][2] + rs[h][3]);
    lg[h][tid] *= inv;
    lg[h][tid + 256] *= inv;
  }
  __syncthreads();   // lg now holds a

  float* crow = catm + (size_t)bi * CATW;
  int j0 = wid * 128;   // this wave's j window

  // ---- o / o_hp partials: wave-split over j ----
  for (int t = lane; t < 480; t += 64) {
    const float* src;
    int h, str;
    if (t < 192) { h = t >> 4; src = vw + (size_t)b * NN * 192 + t; str = 192; }
    else { int f = t - 192; h = f / 24; src = tvw + (size_t)b * NN * 288 + f; str = 288; }
    float sum = 0.f;
    for (int jj = 0; jj < 128; jj += 4) {
      float4 av = *(const float4*)&lg[h][j0 + jj];
      sum += av.x * src[(size_t)(j0 + jj + 0) * str]
           + av.y * src[(size_t)(j0 + jj + 1) * str]
           + av.z * src[(size_t)(j0 + jj + 2) * str]
           + av.w * src[(size_t)(j0 + jj + 3) * str];
    }
    opart[wid][t] = sum;
  }
  __syncthreads();
  for (int t = tid; t < 480; t += 256) {
    float s = opart[0][t] + opart[1][t] + opart[2][t] + opart[3][t];
    if (t < 192) crow[1536 + t] = s;
    else praw[t - 192] = s;
  }
  __syncthreads();
  for (int f = tid; f < 288; f += 256) {
    int g = f / 3, x = f % 3;
    float v0 = praw[g * 3 + 0] - T[0];
    float v1 = praw[g * 3 + 1] - T[1];
    float v2 = praw[g * 3 + 2] - T[2];
    float val = R[0 * 3 + x] * v0 + R[1 * 3 + x] * v1 + R[2 * 3 + x] * v2;
    ohp[f] = val;
    crow[1728 + f] = val;
  }
  __syncthreads();
  if (tid < 96) {
    float x0 = ohp[tid * 3 + 0];
    float x1 = ohp[tid * 3 + 1];
    float x2 = ohp[tid * 3 + 2];
    crow[2016 + tid] = sqrtf(x0 * x0 + x1 * x1 + x2 * x2);
  }

  // ---- o_hat: stream z (second pass), half-wave j-split, float4 c ----
  int hw = lane >> 5, c4 = (lane & 31) * 4;
  float4 acc[HH];
  #pragma unroll
  for (int h = 0; h < HH; h++) acc[h] = make_float4(0.f, 0.f, 0.f, 0.f);
  for (int stp = 0; stp < 64; stp++) {
    int j = j0 + stp * 2 + hw;
    float4 zv = *(const float4*)(z + ((size_t)bi * NN + j) * CZ + c4);
    #pragma unroll
    for (int h = 0; h < HH; h++) {
      float a = lg[h][j];
      acc[h].x += a * zv.x;
      acc[h].y += a * zv.y;
      acc[h].z += a * zv.z;
      acc[h].w += a * zv.w;
    }
  }
  __syncthreads();   // all reads of lg complete everywhere; safe to reuse
  #pragma unroll
  for (int h = 0; h < HH; h++) {
    acc[h].x += __shfl_xor(acc[h].x, 32, 64);
    acc[h].y += __shfl_xor(acc[h].y, 32, 64);
    acc[h].z += __shfl_xor(acc[h].z, 32, 64);
    acc[h].w += __shfl_xor(acc[h].w, 32, 64);
  }
  float* pbuf = &lg[0][0];
  if (lane < 32) {
    #pragma unroll
    for (int h = 0; h < HH; h++)
      *(float4*)&pbuf[wid * 1536 + h * 128 + lane * 4] = acc[h];
  }
  __syncthreads();
  #pragma unroll
  for (int s = 0; s < 6; s++) {
    int idx = tid + s * 256;
    crow[idx] = pbuf[idx] + pbuf[1536 + idx] + pbuf[3072 + idx] + pbuf[4608 + idx];
  }
}

// ---------------- Kernel 4: output GEMM, split-K=4, 64x64, 4x4 reg tile ---
#define KCH 528
__global__ void k_gemm(const float* __restrict__ catm,
                       const float* __restrict__ wout,
                       float* __restrict__ pout) {
  __shared__ float As[16][68];   // [kk][m], padded
  __shared__ float Bs[16][64];   // [kk][n]
  int tid = threadIdx.x;
  int n0 = blockIdx.x * 64, m0 = blockIdx.y * 64, kbase = blockIdx.z * KCH;
  int tx = tid & 15, ty = tid >> 4;
  int sm = tid & 63, skk4 = tid >> 6;
  int bkk = tid >> 4, bn4 = (tid & 15) * 4;
  float acc[4][4] = {};
  for (int kt = 0; kt < KCH / 16; kt++) {
    int k0 = kbase + kt * 16;
    float4 ga = *(const float4*)(catm + (size_t)(m0 + sm) * CATW + k0 + skk4 * 4);
    float4 gb = *(const float4*)(wout + (size_t)(k0 + bkk) * 384 + n0 + bn4);
    __syncthreads();
    As[skk4 * 4 + 0][sm] = ga.x;
    As[skk4 * 4 + 1][sm] = ga.y;
    As[skk4 * 4 + 2][sm] = ga.z;
    As[skk4 * 4 + 3][sm] = ga.w;
    *(float4*)&Bs[bkk][bn4] = gb;
    __syncthreads();
    #pragma unroll
    for (int kk = 0; kk < 16; kk++) {
      float4 av = *(const float4*)&As[kk][ty * 4];
      float4 bv = *(const float4*)&Bs[kk][tx * 4];
      acc[0][0] += av.x * bv.x; acc[0][1] += av.x * bv.y; acc[0][2] += av.x * bv.z; acc[0][3] += av.x * bv.w;
      acc[1][0] += av.y * bv.x; acc[1][1] += av.y * bv.y; acc[1][2] += av.y * bv.z; acc[1][3] += av.y * bv.w;
      acc[2][0] += av.z * bv.x; acc[2][1] += av.z * bv.y; acc[2][2] += av.z * bv.z; acc[2][3] += av.z * bv.w;
      acc[3][0] += av.w * bv.x; acc[3][1] += av.w * bv.y; acc[3][2] += av.w * bv.z; acc[3][3] += av.w * bv.w;
    }
  }
  float* pdst = pout + (size_t)blockIdx.z * (1024 * 384);
  #pragma unroll
  for (int mm = 0; mm < 4; mm++) {
    *(float4*)&pdst[(size_t)(m0 + ty * 4 + mm) * 384 + n0 + tx * 4] =
        make_float4(acc[mm][0], acc[mm][1], acc[mm][2], acc[mm][3]);
  }
}

// ---------------- Kernel 5: split-K reduce + bias ----
__global__ void k_red(const float* __restrict__ pout,
                      const float* __restrict__ bout,
                      float* __restrict__ out) {
  int idx = blockIdx.x * 256 + threadIdx.x;
  const int TOTAL = 1024 * 384;
  float s = pout[idx] + pout[TOTAL + idx] + pout[2 * TOTAL + idx] + pout[3 * TOTAL + idx];
  out[idx] = s + bout[idx % 384];
}

extern "C" void kernel_launch(void* const* d_in, const int* in_sizes, int n_in,
                              void* d_out, int out_size, void* d_ws, size_t ws_size,
                              hipStream_t stream) {
  const float* s_i   = (const float*)d_in[0];
  const float* z     = (const float*)d_in[1];
  const float* rots  = (const float*)d_in[2];
  const float* trans = (const float*)d_in[3];
  const float* wq    = (const float*)d_in[4];
  const float* wk    = (const float*)d_in[5];
  const float* wv    = (const float*)d_in[6];
  const float* wqp   = (const float*)d_in[7];
  const float* wkp   = (const float*)d_in[8];
  const float* wvp   = (const float*)d_in[9];
  const float* wb    = (const float*)d_in[10];
  const float* gamma = (const float*)d_in[11];
  const float* wout  = (const float*)d_in[12];
  const float* bout  = (const float*)d_in[13];
  float* out = (float*)d_out;

  float* ws = (float*)d_ws;
  const size_t TOK = (size_t)BB * NN;  // 1024
  float* qw  = ws;                      // TOK*192
  float* kw  = qw + TOK * 192;
  float* vw  = kw + TOK * 192;
  float* tqw = vw + TOK * 192;          // TOK*144
  float* tkw = tqw + TOK * 144;
  float* tvw = tkw + TOK * 144;         // TOK*288
  float* bw  = tvw + TOK * 288;         // TOK*H*N bias
  float* catm = bw + TOK * HH * NN;     // TOK*2112
  float* pout = catm + TOK * CATW;      // 4*1024*384

  k_proj<<<BB * NN / 2, 256, 0, stream>>>(s_i, rots, trans, wq, wk, wv, wqp, wkp, wvp,
                                          qw, kw, vw, tqw, tkw, tvw);
  k_bias<<<BB * NN * NN / BR, 256, 0, stream>>>(z, wb, bw);
  k_att<<<BB * NN, 256, 0, stream>>>(z, qw, kw, tqw, tkw, vw, tvw, gamma, rots, trans,
                                     bw, catm);
  dim3 gg(6, 16, 4);
  k_gemm<<<gg, 256, 0, stream>>>(catm, wout, pout);
  k_red<<<(1024 * 384) / 256, 256, 0, stream>>>(pout, bout, out);
}